// Round 8
// baseline (256.468 us; speedup 1.0000x reference)
//
#include <hip/hip_runtime.h>
#include <hip/hip_bf16.h>

#define NB   8
#define CC   256
#define NN   4096            // H*W
#define NTOT (NB*NN)         // 32768
#define DQK  32
#define DV   128

typedef __attribute__((ext_vector_type(8))) short bf16x8;    // 8 bf16 in 4 VGPRs
typedef __attribute__((ext_vector_type(4))) float f32x4;
typedef __attribute__((ext_vector_type(16))) float f32x16;
typedef __attribute__((ext_vector_type(4))) float float4v;
typedef __attribute__((ext_vector_type(4))) unsigned int u32x4;

__device__ __forceinline__ short f2bf(float f) {
    __hip_bfloat16 h = __float2bfloat16(f);
    return *reinterpret_cast<short*>(&h);
}
__device__ __forceinline__ float bf2f(short s) {
    unsigned int u = ((unsigned int)(unsigned short)s) << 16;
    return __builtin_bit_cast(float, u);
}
__device__ __forceinline__ unsigned int cvtpk(float lo, float hi) {
    unsigned int r;
    asm("v_cvt_pk_bf16_f32 %0, %1, %2" : "=v"(r) : "v"(lo), "v"(hi));
    return r;
}
// v_permlane32_swap_b32 a, b: a' = [a(0:31), b(0:31)], b' = [a(32:63), b(32:63)]
__device__ __forceinline__ void plswap(unsigned int &a, unsigned int &b) {
    asm("v_permlane32_swap_b32 %0, %1" : "+v"(a), "+v"(b));
}

// -------- workspace layout (bytes) --------
#define OFF_F     0u                        // f  bf16 [NTOT][32]        2 MB
#define OFF_G     (2u<<20)                  // g  bf16 [NTOT][32]        2 MB (pre-scaled log2e)
#define OFF_VT    (4u<<20)                  // vtile bf16 (frag-tiled)   8 MB
#define OFF_OP    (12u<<20)                 // opart bf16 [NTOT][2][128] 16 MB
#define OFF_LS    (28u<<20)                 // lspart f32 [NTOT][2]      256 KB
#define OFF_WQKVT ((28u<<20)+(512u<<10))    // WqkvT bf16 [192][256]     96 KB
#define OFF_WOT   (OFF_WQKVT + 192u*256u*2u) // WoT bf16 [256][128]      64 KB

// ---------------- prep: transpose weights to bf16 ----------------
__global__ __launch_bounds__(256) void prep_kernel(
    const float* __restrict__ Wf, const float* __restrict__ Wg,
    const float* __restrict__ Wh, const float* __restrict__ Wo,
    short* __restrict__ WqkvT, short* __restrict__ WoT)
{
    int idx = blockIdx.x * 256 + threadIdx.x;
    if (idx < 192 * 256) {
        int j = idx >> 8, k = idx & 255;
        float v = (j < 32) ? Wf[k * 32 + j]
                : (j < 64) ? Wg[k * 32 + (j - 32)]
                           : Wh[k * 128 + (j - 64)];
        WqkvT[j * 256 + k] = f2bf(v);
    }
    int i2 = idx - 192 * 256;
    if (i2 >= 0 && i2 < 256 * 128) {
        int c = i2 >> 7, d = i2 & 127;
        WoT[c * 128 + d] = f2bf(Wo[d * 256 + c]);
    }
}

// ---------------- proj: [f|g|hv] = x @ [Wf|Wg|Wh] + bias ----------------
// g pre-scaled by log2(e). hv written in MFMA-A-frag-tiled order:
// vtile element (b, n, d):
//   kt = n>>6, kslot = (n>>4)&3, lh = (n>>3)&1, j = n&7, dt = d>>5, l31 = d&31
//   addr = ((b*64+kt)*4 + kslot)*2048 + dt*512 + lh*256 + l31*8 + j
__global__ __launch_bounds__(256) void proj_kernel(
    const float* __restrict__ x,
    const float* __restrict__ bf_, const float* __restrict__ bg_,
    const float* __restrict__ bh_,
    const short* __restrict__ WqkvT,
    short* __restrict__ fws, short* __restrict__ gws, short* __restrict__ vtile)
{
    int wid = threadIdx.x >> 6, lane = threadIdx.x & 63;
    int col16 = lane & 15, rq = lane >> 4;
    int rbase = blockIdx.x * 64 + wid * 16;
    int arow = rbase + col16;

    f32x4 acc[12];
    #pragma unroll
    for (int i = 0; i < 12; ++i) acc[i] = (f32x4){0.f, 0.f, 0.f, 0.f};

    const float* xrow = x + (size_t)arow * CC;
    #pragma unroll
    for (int kk = 0; kk < 8; ++kk) {
        int k0 = kk * 32 + rq * 8;
        float4v u0 = *(const float4v*)(xrow + k0);
        float4v u1 = *(const float4v*)(xrow + k0 + 4);
        bf16x8 av;
        av[0]=f2bf(u0[0]); av[1]=f2bf(u0[1]); av[2]=f2bf(u0[2]); av[3]=f2bf(u0[3]);
        av[4]=f2bf(u1[0]); av[5]=f2bf(u1[1]); av[6]=f2bf(u1[2]); av[7]=f2bf(u1[3]);
        #pragma unroll
        for (int nf = 0; nf < 12; ++nf) {
            bf16x8 bv = *(const bf16x8*)(WqkvT + (nf * 16 + col16) * 256 + k0);
            acc[nf] = __builtin_amdgcn_mfma_f32_16x16x32_bf16(av, bv, acc[nf], 0, 0, 0);
        }
    }

    #pragma unroll
    for (int nf = 0; nf < 12; ++nf) {
        int colg = nf * 16 + col16;
        #pragma unroll
        for (int r = 0; r < 4; ++r) {
            int rowg = rbase + rq * 4 + r;
            float val = acc[nf][r];
            if (colg < 32) {
                fws[(size_t)rowg * DQK + colg] = f2bf(val + bf_[colg]);
            } else if (colg < 64) {
                int c = colg - 32;
                gws[(size_t)rowg * DQK + c] = f2bf((val + bg_[c]) * 1.44269504089f);
            } else {
                int d = colg - 64;
                int b = rowg >> 12, n = rowg & 4095;
                int kt = n >> 6, kslot = (n >> 4) & 3, klh = (n >> 3) & 1, j = n & 7;
                size_t addr = (((size_t)(b * 64 + kt) * 4 + kslot) * 2048)
                            + (d >> 5) * 512 + klh * 256 + (d & 31) * 8 + j;
                vtile[addr] = f2bf(val + bh_[d]);
            }
        }
    }
}

// ---------------- attn: barrier-free loop, full reg double-buffer ----------
// 1024 blocks (8 b x 2 ksh x 64 qtiles) x 256 thr.
// Wave (qh, kh): QK^T quadrant (swapped: s[k][q], lane=q) -> exp2 -> pack ->
// PV transposed oT[d][q] = mfma(va, pb). BOTH f and va register double-
// buffered one full iteration ahead (even/odd named reg sets): every global
// load has ~1 compute block of latency slack. setprio(1) around PV cluster.
// No LDS/barriers in loop. Epilogue: kh merge + transpose via LDS.
__global__ __launch_bounds__(256, 3) void attn_kernel(
    const short* __restrict__ fws, const short* __restrict__ gws,
    const short* __restrict__ vtile, short* __restrict__ opart,
    float* __restrict__ lspart)
{
    __shared__ __align__(16) char smem[33280];  // 32KB obuf + 512B lsbuf

    int t = threadIdx.x;
    int wid = t >> 6, lane = t & 63;
    int l31 = lane & 31, lh = lane >> 5;
    int qh = wid >> 1, kh = wid & 1;

    // XCD-aware swizzle: 1024 wgs % 8 == 0 -> bijective; batch per XCD
    int bid = blockIdx.x;
    int sid = (bid & 7) * 128 + (bid >> 3);
    int b = sid >> 7, rem = sid & 127;
    int ksh = rem >> 6, qt = rem & 63;
    int qbase = b * NN + qt * 64;
    int k0 = ksh * 32, kend = k0 + 32;   // 64-key tiles

    // g B-frags (col = q = qh*32+l31, k-elem = cs*16 + lh*8 + j)
    const short* grow = gws + (size_t)(qbase + qh * 32 + l31) * DQK;
    bf16x8 gb0 = *(const bf16x8*)(grow + lh * 8);
    bf16x8 gb1 = *(const bf16x8*)(grow + 16 + lh * 8);

    // f A-frags: row(key) = kb*64 + kh*32 + l31, elems = cs*16 + lh*8 + j
    int foff = (kh * 32 + l31) * DQK + lh * 8;
    const short* fS = fws + (size_t)b * NN * DQK;
    // va frag base: + kb*8192 per tile; 8 frags at ks*2048 + dt*512
    const short* vS = vtile + ((size_t)b * 64 * 4) * 2048 + (kh * 2) * 2048
                    + (size_t)lane * 8;

    f32x16 oaccT[4], zero16;
    #pragma unroll
    for (int i = 0; i < 16; ++i) {
        zero16[i] = 0.f;
        oaccT[0][i] = 0.f; oaccT[1][i] = 0.f; oaccT[2][i] = 0.f; oaccT[3][i] = 0.f;
    }
    float lsum = 0.f;

#define LOADSET(F0, F1, V0, V1, V2, V3, V4, V5, V6, V7, KB) {              \
    int kc_ = (KB) < kend ? (KB) : kend - 1;                               \
    const short* fp_ = fS + (size_t)kc_ * 2048 + foff;                     \
    F0 = *(const bf16x8*)(fp_);                                            \
    F1 = *(const bf16x8*)(fp_ + 16);                                       \
    const short* vp_ = vS + (size_t)kc_ * 8192;                            \
    V0 = *(const bf16x8*)(vp_);                                            \
    V1 = *(const bf16x8*)(vp_ + 512);                                      \
    V2 = *(const bf16x8*)(vp_ + 1024);                                     \
    V3 = *(const bf16x8*)(vp_ + 1536);                                     \
    V4 = *(const bf16x8*)(vp_ + 2048);                                     \
    V5 = *(const bf16x8*)(vp_ + 2560);                                     \
    V6 = *(const bf16x8*)(vp_ + 3072);                                     \
    V7 = *(const bf16x8*)(vp_ + 3584);                                     \
}

#define COMPUTE(F0, F1, V0, V1, V2, V3, V4, V5, V6, V7) {                  \
    f32x16 s_ = __builtin_amdgcn_mfma_f32_32x32x16_bf16(F0, gb0, zero16, 0, 0, 0); \
    s_ = __builtin_amdgcn_mfma_f32_32x32x16_bf16(F1, gb1, s_, 0, 0, 0);    \
    unsigned int w_[8];                                                    \
    _Pragma("unroll")                                                      \
    for (int i_ = 0; i_ < 8; ++i_) {                                       \
        float pa_ = __builtin_exp2f(s_[2 * i_]);                           \
        float pb_ = __builtin_exp2f(s_[2 * i_ + 1]);                       \
        lsum += pa_ + pb_;                                                 \
        w_[i_] = cvtpk(pa_, pb_);                                          \
    }                                                                      \
    plswap(w_[0], w_[2]); plswap(w_[1], w_[3]);                            \
    plswap(w_[4], w_[6]); plswap(w_[5], w_[7]);                            \
    u32x4 pw0_ = { w_[0], w_[1], w_[2], w_[3] };                           \
    u32x4 pw1_ = { w_[4], w_[5], w_[6], w_[7] };                           \
    bf16x8 p0_ = __builtin_bit_cast(bf16x8, pw0_);                         \
    bf16x8 p1_ = __builtin_bit_cast(bf16x8, pw1_);                         \
    __builtin_amdgcn_s_setprio(1);                                         \
    oaccT[0] = __builtin_amdgcn_mfma_f32_32x32x16_bf16(V0, p0_, oaccT[0], 0, 0, 0); \
    oaccT[1] = __builtin_amdgcn_mfma_f32_32x32x16_bf16(V1, p0_, oaccT[1], 0, 0, 0); \
    oaccT[2] = __builtin_amdgcn_mfma_f32_32x32x16_bf16(V2, p0_, oaccT[2], 0, 0, 0); \
    oaccT[3] = __builtin_amdgcn_mfma_f32_32x32x16_bf16(V3, p0_, oaccT[3], 0, 0, 0); \
    oaccT[0] = __builtin_amdgcn_mfma_f32_32x32x16_bf16(V4, p1_, oaccT[0], 0, 0, 0); \
    oaccT[1] = __builtin_amdgcn_mfma_f32_32x32x16_bf16(V5, p1_, oaccT[1], 0, 0, 0); \
    oaccT[2] = __builtin_amdgcn_mfma_f32_32x32x16_bf16(V6, p1_, oaccT[2], 0, 0, 0); \
    oaccT[3] = __builtin_amdgcn_mfma_f32_32x32x16_bf16(V7, p1_, oaccT[3], 0, 0, 0); \
    __builtin_amdgcn_s_setprio(0);                                         \
}

    bf16x8 fa0, fa1, a0, a1, a2, a3, a4, a5, a6, a7;
    bf16x8 fb0, fb1, b0, b1, b2, b3, b4, b5, b6, b7;

    LOADSET(fa0, fa1, a0, a1, a2, a3, a4, a5, a6, a7, k0);
    for (int kb = k0; kb < kend; kb += 2) {
        LOADSET(fb0, fb1, b0, b1, b2, b3, b4, b5, b6, b7, kb + 1);
        COMPUTE(fa0, fa1, a0, a1, a2, a3, a4, a5, a6, a7);
        LOADSET(fa0, fa1, a0, a1, a2, a3, a4, a5, a6, a7, kb + 2);
        COMPUTE(fb0, fb1, b0, b1, b2, b3, b4, b5, b6, b7);
    }
#undef LOADSET
#undef COMPUTE

    // ---- epilogue: kh merge + transpose via XOR-chunked LDS ----
    lsum += __shfl_xor(lsum, 32);               // combine lh halves (same q)
    float* lsbuf = (float*)(&smem[32768]);
    if (lh == 0) lsbuf[(qh * 2 + kh) * 32 + l31] = lsum;
    __syncthreads();                            // E1

    // obuf: [64 q][512B row = 32 f32x4 chunks, phys chunk = c ^ (q&31)]
    char* obuf = smem;
    if (kh == 1) {
        #pragma unroll
        for (int dt = 0; dt < 4; ++dt) {
            #pragma unroll
            for (int r = 0; r < 16; ++r) {
                int d = dt * 32 + (r & 3) + 8 * (r >> 2) + 4 * lh;
                int q = qh * 32 + l31;
                int byte = q * 512 + ((((d >> 2) ^ (q & 31)) << 4) | ((d & 3) << 2));
                *(float*)(obuf + byte) = oaccT[dt][r];
            }
        }
    }
    __syncthreads();                            // E2
    if (kh == 0) {
        float tot = lsbuf[qh * 64 + l31] + lsbuf[qh * 64 + 32 + l31];
        if (lh == 0) lspart[(size_t)(qbase + qh * 32 + l31) * 2 + ksh] = tot;
        float iv = 1.f / tot;
        #pragma unroll
        for (int dt = 0; dt < 4; ++dt) {
            #pragma unroll
            for (int r = 0; r < 16; ++r) {
                int d = dt * 32 + (r & 3) + 8 * (r >> 2) + 4 * lh;
                int q = qh * 32 + l31;
                int byte = q * 512 + ((((d >> 2) ^ (q & 31)) << 4) | ((d & 3) << 2));
                float* p = (float*)(obuf + byte);
                *p = (*p + oaccT[dt][r]) * iv;
            }
        }
    }
    __syncthreads();                            // E3
    // coop convert + coalesced store: t -> q = t>>2, dg = t&3 (32 d values)
    {
        int q = t >> 2, dg = t & 3;
        size_t orow = ((size_t)(qbase + q) * 2 + ksh) * 128 + dg * 32;
        #pragma unroll
        for (int cc = 0; cc < 8; cc += 2) {
            int c0 = dg * 8 + cc;
            f32x4 u0 = *(const f32x4*)(obuf + q * 512 + (((c0 ^ (q & 31)) << 4)));
            f32x4 u1 = *(const f32x4*)(obuf + q * 512 + ((((c0 + 1) ^ (q & 31)) << 4)));
            bf16x8 ov;
            ov[0]=f2bf(u0[0]); ov[1]=f2bf(u0[1]); ov[2]=f2bf(u0[2]); ov[3]=f2bf(u0[3]);
            ov[4]=f2bf(u1[0]); ov[5]=f2bf(u1[1]); ov[6]=f2bf(u1[2]); ov[7]=f2bf(u1[3]);
            *(bf16x8*)(opart + orow + cc * 4) = ov;
        }
    }
}

// ---------------- out: combine k-halves, then gamma*(o@Wo + bo) + x ----------
__global__ __launch_bounds__(256) void out_kernel(
    const short* __restrict__ opart, const float* __restrict__ lspart,
    const short* __restrict__ WoT,
    const float* __restrict__ bo, const float* __restrict__ gamma,
    const float* __restrict__ x, float* __restrict__ out)
{
    int wid = threadIdx.x >> 6, lane = threadIdx.x & 63;
    int col16 = lane & 15, rq = lane >> 4;
    int rbase = blockIdx.x * 64 + wid * 16;
    int arow = rbase + col16;

    float l0 = lspart[(size_t)arow * 2];
    float l1 = lspart[(size_t)arow * 2 + 1];
    float iv = 1.f / (l0 + l1);
    float w0 = l0 * iv, w1 = l1 * iv;

    const short* oprow = opart + (size_t)arow * 256;
    bf16x8 afr[4];
    #pragma unroll
    for (int kk = 0; kk < 4; ++kk) {
        bf16x8 a0 = *(const bf16x8*)(oprow + kk * 32 + rq * 8);
        bf16x8 a1 = *(const bf16x8*)(oprow + 128 + kk * 32 + rq * 8);
        bf16x8 af;
        #pragma unroll
        for (int j = 0; j < 8; ++j)
            af[j] = f2bf(w0 * bf2f(a0[j]) + w1 * bf2f(a1[j]));
        afr[kk] = af;
    }

    f32x4 acc[16];
    #pragma unroll
    for (int i = 0; i < 16; ++i) acc[i] = (f32x4){0.f, 0.f, 0.f, 0.f};

    #pragma unroll
    for (int nf = 0; nf < 16; ++nf) {
        #pragma unroll
        for (int kk = 0; kk < 4; ++kk) {
            bf16x8 bfr = *(const bf16x8*)(WoT + (nf * 16 + col16) * DV + kk * 32 + rq * 8);
            acc[nf] = __builtin_amdgcn_mfma_f32_16x16x32_bf16(afr[kk], bfr, acc[nf], 0, 0, 0);
        }
    }

    float gm = gamma[0];
    #pragma unroll
    for (int nf = 0; nf < 16; ++nf) {
        int colg = nf * 16 + col16;
        float bov = bo[colg];
        #pragma unroll
        for (int r = 0; r < 4; ++r) {
            int rowg = rbase + rq * 4 + r;
            out[(size_t)rowg * CC + colg] = gm * (acc[nf][r] + bov) + x[(size_t)rowg * CC + colg];
        }
    }
}

extern "C" void kernel_launch(void* const* d_in, const int* in_sizes, int n_in,
                              void* d_out, int out_size, void* d_ws, size_t ws_size,
                              hipStream_t stream)
{
    const float* x     = (const float*)d_in[0];
    const float* Wf    = (const float*)d_in[1];
    const float* bf_   = (const float*)d_in[2];
    const float* Wg    = (const float*)d_in[3];
    const float* bg_   = (const float*)d_in[4];
    const float* Wh    = (const float*)d_in[5];
    const float* bh_   = (const float*)d_in[6];
    const float* Wo    = (const float*)d_in[7];
    const float* bo    = (const float*)d_in[8];
    const float* gamma = (const float*)d_in[9];

    char* ws = (char*)d_ws;
    short* fws   = (short*)(ws + OFF_F);
    short* gws   = (short*)(ws + OFF_G);
    short* vtile = (short*)(ws + OFF_VT);
    short* opart = (short*)(ws + OFF_OP);
    float* lsp   = (float*)(ws + OFF_LS);
    short* WqkvT = (short*)(ws + OFF_WQKVT);
    short* WoT   = (short*)(ws + OFF_WOT);
    float* out   = (float*)d_out;

    hipLaunchKernelGGL(prep_kernel, dim3(320), dim3(256), 0, stream, Wf, Wg, Wh, Wo, WqkvT, WoT);
    hipLaunchKernelGGL(proj_kernel, dim3(512), dim3(256), 0, stream,
                       x, bf_, bg_, bh_, WqkvT, fws, gws, vtile);
    hipLaunchKernelGGL(attn_kernel, dim3(1024), dim3(256), 0, stream, fws, gws, vtile, opart, lsp);
    hipLaunchKernelGGL(out_kernel, dim3(512), dim3(256), 0, stream, opart, lsp, WoT, bo, gamma, x, out);
}

// Round 9
// 141.279 us; speedup vs baseline: 1.8153x; 1.8153x over previous
//
#include <hip/hip_runtime.h>
#include <hip/hip_bf16.h>

#define NB   8
#define CC   256
#define NN   4096            // H*W
#define NTOT (NB*NN)         // 32768
#define DQK  32
#define DV   128

typedef __attribute__((ext_vector_type(8))) short bf16x8;    // 8 bf16 in 4 VGPRs
typedef __attribute__((ext_vector_type(4))) float f32x4;
typedef __attribute__((ext_vector_type(16))) float f32x16;
typedef __attribute__((ext_vector_type(4))) float float4v;
typedef __attribute__((ext_vector_type(4))) unsigned int u32x4;

__device__ __forceinline__ short f2bf(float f) {
    __hip_bfloat16 h = __float2bfloat16(f);
    return *reinterpret_cast<short*>(&h);
}
__device__ __forceinline__ float bf2f(short s) {
    unsigned int u = ((unsigned int)(unsigned short)s) << 16;
    return __builtin_bit_cast(float, u);
}
__device__ __forceinline__ unsigned int cvtpk(float lo, float hi) {
    unsigned int r;
    asm("v_cvt_pk_bf16_f32 %0, %1, %2" : "=v"(r) : "v"(lo), "v"(hi));
    return r;
}
// v_permlane32_swap_b32 a, b: a' = [a(0:31), b(0:31)], b' = [a(32:63), b(32:63)]
__device__ __forceinline__ void plswap(unsigned int &a, unsigned int &b) {
    asm("v_permlane32_swap_b32 %0, %1" : "+v"(a), "+v"(b));
}

// -------- workspace layout (bytes) --------
#define OFF_F     0u                        // f  bf16 [NTOT][32]        2 MB
#define OFF_G     (2u<<20)                  // g  bf16 [NTOT][32]        2 MB (pre-scaled log2e)
#define OFF_VT    (4u<<20)                  // vtile bf16 (frag-tiled)   8 MB
#define OFF_OP    (12u<<20)                 // opart bf16 [NTOT][2][128] 16 MB
#define OFF_LS    (28u<<20)                 // lspart f32 [NTOT][2]      256 KB
#define OFF_WQKVT ((28u<<20)+(512u<<10))    // WqkvT bf16 [192][256]     96 KB
#define OFF_WOT   (OFF_WQKVT + 192u*256u*2u) // WoT bf16 [256][128]      64 KB

// ---------------- prep: transpose weights to bf16 ----------------
__global__ __launch_bounds__(256) void prep_kernel(
    const float* __restrict__ Wf, const float* __restrict__ Wg,
    const float* __restrict__ Wh, const float* __restrict__ Wo,
    short* __restrict__ WqkvT, short* __restrict__ WoT)
{
    int idx = blockIdx.x * 256 + threadIdx.x;
    if (idx < 192 * 256) {
        int j = idx >> 8, k = idx & 255;
        float v = (j < 32) ? Wf[k * 32 + j]
                : (j < 64) ? Wg[k * 32 + (j - 32)]
                           : Wh[k * 128 + (j - 64)];
        WqkvT[j * 256 + k] = f2bf(v);
    }
    int i2 = idx - 192 * 256;
    if (i2 >= 0 && i2 < 256 * 128) {
        int c = i2 >> 7, d = i2 & 127;
        WoT[c * 128 + d] = f2bf(Wo[d * 256 + c]);
    }
}

// ---------------- proj: [f|g|hv] = x @ [Wf|Wg|Wh] + bias ----------------
// g pre-scaled by log2(e). hv written in MFMA-A-frag-tiled order:
// vtile element (b, n, d):
//   kt = n>>6, kslot = (n>>4)&3, lh = (n>>3)&1, j = n&7, dt = d>>5, l31 = d&31
//   addr = ((b*64+kt)*4 + kslot)*2048 + dt*512 + lh*256 + l31*8 + j
__global__ __launch_bounds__(256) void proj_kernel(
    const float* __restrict__ x,
    const float* __restrict__ bf_, const float* __restrict__ bg_,
    const float* __restrict__ bh_,
    const short* __restrict__ WqkvT,
    short* __restrict__ fws, short* __restrict__ gws, short* __restrict__ vtile)
{
    int wid = threadIdx.x >> 6, lane = threadIdx.x & 63;
    int col16 = lane & 15, rq = lane >> 4;
    int rbase = blockIdx.x * 64 + wid * 16;
    int arow = rbase + col16;

    f32x4 acc[12];
    #pragma unroll
    for (int i = 0; i < 12; ++i) acc[i] = (f32x4){0.f, 0.f, 0.f, 0.f};

    const float* xrow = x + (size_t)arow * CC;
    #pragma unroll
    for (int kk = 0; kk < 8; ++kk) {
        int k0 = kk * 32 + rq * 8;
        float4v u0 = *(const float4v*)(xrow + k0);
        float4v u1 = *(const float4v*)(xrow + k0 + 4);
        bf16x8 av;
        av[0]=f2bf(u0[0]); av[1]=f2bf(u0[1]); av[2]=f2bf(u0[2]); av[3]=f2bf(u0[3]);
        av[4]=f2bf(u1[0]); av[5]=f2bf(u1[1]); av[6]=f2bf(u1[2]); av[7]=f2bf(u1[3]);
        #pragma unroll
        for (int nf = 0; nf < 12; ++nf) {
            bf16x8 bv = *(const bf16x8*)(WqkvT + (nf * 16 + col16) * 256 + k0);
            acc[nf] = __builtin_amdgcn_mfma_f32_16x16x32_bf16(av, bv, acc[nf], 0, 0, 0);
        }
    }

    #pragma unroll
    for (int nf = 0; nf < 12; ++nf) {
        int colg = nf * 16 + col16;
        #pragma unroll
        for (int r = 0; r < 4; ++r) {
            int rowg = rbase + rq * 4 + r;
            float val = acc[nf][r];
            if (colg < 32) {
                fws[(size_t)rowg * DQK + colg] = f2bf(val + bf_[colg]);
            } else if (colg < 64) {
                int c = colg - 32;
                gws[(size_t)rowg * DQK + c] = f2bf((val + bg_[c]) * 1.44269504089f);
            } else {
                int d = colg - 64;
                int b = rowg >> 12, n = rowg & 4095;
                int kt = n >> 6, kslot = (n >> 4) & 3, klh = (n >> 3) & 1, j = n & 7;
                size_t addr = (((size_t)(b * 64 + kt) * 4 + kslot) * 2048)
                            + (d >> 5) * 512 + klh * 256 + (d & 31) * 8 + j;
                vtile[addr] = f2bf(val + bh_[d]);
            }
        }
    }
}

// ---------------- attn: barrier-free loop, early-issued va loads ------------
// 1024 blocks (8 b x 2 ksh x 64 qtiles) x 256 thr; 3 blocks/CU (reg-bound).
// Wave (qh, kh): QK^T quadrant (swapped: s[k][q], lane=q) -> exp2 -> pack ->
// PV transposed oT[d][q] = mfma(va, pb). The 8 va loads for the CURRENT
// iteration are issued right after the QK^T MFMAs, so the ~250cy softmax
// chain hides their L2 latency (no extra double-buffer registers — R8's
// spill lesson). f single-prefetched one iter ahead. setprio around PV.
__global__ __launch_bounds__(256, 3) void attn_kernel(
    const short* __restrict__ fws, const short* __restrict__ gws,
    const short* __restrict__ vtile, short* __restrict__ opart,
    float* __restrict__ lspart)
{
    __shared__ __align__(16) char smem[33280];  // 32KB obuf + 512B lsbuf

    int t = threadIdx.x;
    int wid = t >> 6, lane = t & 63;
    int l31 = lane & 31, lh = lane >> 5;
    int qh = wid >> 1, kh = wid & 1;

    // XCD-aware swizzle: 1024 wgs % 8 == 0 -> bijective; batch per XCD
    int bid = blockIdx.x;
    int sid = (bid & 7) * 128 + (bid >> 3);
    int b = sid >> 7, rem = sid & 127;
    int ksh = rem >> 6, qt = rem & 63;
    int qbase = b * NN + qt * 64;
    int k0 = ksh * 32, kend = k0 + 32;   // 64-key tiles

    // g B-frags (col = q = qh*32+l31, k-elem = cs*16 + lh*8 + j)
    const short* grow = gws + (size_t)(qbase + qh * 32 + l31) * DQK;
    bf16x8 gb0 = *(const bf16x8*)(grow + lh * 8);
    bf16x8 gb1 = *(const bf16x8*)(grow + 16 + lh * 8);

    // f A-frags: row(key) = kb*64 + kh*32 + l31, elems = cs*16 + lh*8 + j
    int foff = (kh * 32 + l31) * DQK + lh * 8;
    const short* fS = fws + (size_t)b * NN * DQK;
    // va frag base: + kb*8192 per tile; 8 frags at ks*2048 + dt*512
    const short* vS = vtile + ((size_t)b * 64 * 4) * 2048 + (kh * 2) * 2048
                    + (size_t)lane * 8;

    f32x16 oaccT[4], zero16;
    #pragma unroll
    for (int i = 0; i < 16; ++i) {
        zero16[i] = 0.f;
        oaccT[0][i] = 0.f; oaccT[1][i] = 0.f; oaccT[2][i] = 0.f; oaccT[3][i] = 0.f;
    }
    float lsum = 0.f;

    bf16x8 fc0 = *(const bf16x8*)(fS + (size_t)k0 * 2048 + foff);
    bf16x8 fc1 = *(const bf16x8*)(fS + (size_t)k0 * 2048 + foff + 16);

    for (int kb = k0; kb < kend; ++kb) {
        // prefetch next f frags (reads past kend land in ws, unused)
        const short* fnp = fS + (size_t)(kb + 1) * 2048 + foff;
        bf16x8 fn0 = *(const bf16x8*)(fnp);
        bf16x8 fn1 = *(const bf16x8*)(fnp + 16);

        // ---- QK^T quadrant: s[k_local][q], lane l31 = q ----
        f32x16 s = __builtin_amdgcn_mfma_f32_32x32x16_bf16(fc0, gb0, zero16, 0, 0, 0);
        s = __builtin_amdgcn_mfma_f32_32x32x16_bf16(fc1, gb1, s, 0, 0, 0);

        // ---- issue ALL va loads now; softmax below hides their latency ----
        const short* vp = vS + (size_t)kb * 8192;
        bf16x8 va[8];
        #pragma unroll
        for (int i = 0; i < 8; ++i)
            va[i] = *(const bf16x8*)(vp + i * 512);

        // ---- p = exp2(s'), per-lane (per-q) sum, pack ----
        unsigned int w[8];
        #pragma unroll
        for (int i = 0; i < 8; ++i) {
            float pa = __builtin_exp2f(s[2 * i]);
            float pb = __builtin_exp2f(s[2 * i + 1]);
            lsum += pa + pb;
            w[i] = cvtpk(pa, pb);
        }
        plswap(w[0], w[2]); plswap(w[1], w[3]);
        plswap(w[4], w[6]); plswap(w[5], w[7]);

        u32x4 pw0 = { w[0], w[1], w[2], w[3] };
        u32x4 pw1 = { w[4], w[5], w[6], w[7] };
        bf16x8 p0 = __builtin_bit_cast(bf16x8, pw0);
        bf16x8 p1 = __builtin_bit_cast(bf16x8, pw1);

        // ---- PV transposed: oT[d][q] += V^T . P^T ----
        __builtin_amdgcn_s_setprio(1);
        oaccT[0] = __builtin_amdgcn_mfma_f32_32x32x16_bf16(va[0], p0, oaccT[0], 0, 0, 0);
        oaccT[1] = __builtin_amdgcn_mfma_f32_32x32x16_bf16(va[1], p0, oaccT[1], 0, 0, 0);
        oaccT[2] = __builtin_amdgcn_mfma_f32_32x32x16_bf16(va[2], p0, oaccT[2], 0, 0, 0);
        oaccT[3] = __builtin_amdgcn_mfma_f32_32x32x16_bf16(va[3], p0, oaccT[3], 0, 0, 0);
        oaccT[0] = __builtin_amdgcn_mfma_f32_32x32x16_bf16(va[4], p1, oaccT[0], 0, 0, 0);
        oaccT[1] = __builtin_amdgcn_mfma_f32_32x32x16_bf16(va[5], p1, oaccT[1], 0, 0, 0);
        oaccT[2] = __builtin_amdgcn_mfma_f32_32x32x16_bf16(va[6], p1, oaccT[2], 0, 0, 0);
        oaccT[3] = __builtin_amdgcn_mfma_f32_32x32x16_bf16(va[7], p1, oaccT[3], 0, 0, 0);
        __builtin_amdgcn_s_setprio(0);

        fc0 = fn0; fc1 = fn1;
    }

    // ---- epilogue: kh merge + transpose via XOR-chunked LDS ----
    lsum += __shfl_xor(lsum, 32);               // combine lh halves (same q)
    float* lsbuf = (float*)(&smem[32768]);
    if (lh == 0) lsbuf[(qh * 2 + kh) * 32 + l31] = lsum;
    __syncthreads();                            // E1

    // obuf: [64 q][512B row = 32 f32x4 chunks, phys chunk = c ^ (q&31)]
    char* obuf = smem;
    if (kh == 1) {
        #pragma unroll
        for (int dt = 0; dt < 4; ++dt) {
            #pragma unroll
            for (int r = 0; r < 16; ++r) {
                int d = dt * 32 + (r & 3) + 8 * (r >> 2) + 4 * lh;
                int q = qh * 32 + l31;
                int byte = q * 512 + ((((d >> 2) ^ (q & 31)) << 4) | ((d & 3) << 2));
                *(float*)(obuf + byte) = oaccT[dt][r];
            }
        }
    }
    __syncthreads();                            // E2
    if (kh == 0) {
        float tot = lsbuf[qh * 64 + l31] + lsbuf[qh * 64 + 32 + l31];
        if (lh == 0) lspart[(size_t)(qbase + qh * 32 + l31) * 2 + ksh] = tot;
        float iv = 1.f / tot;
        #pragma unroll
        for (int dt = 0; dt < 4; ++dt) {
            #pragma unroll
            for (int r = 0; r < 16; ++r) {
                int d = dt * 32 + (r & 3) + 8 * (r >> 2) + 4 * lh;
                int q = qh * 32 + l31;
                int byte = q * 512 + ((((d >> 2) ^ (q & 31)) << 4) | ((d & 3) << 2));
                float* p = (float*)(obuf + byte);
                *p = (*p + oaccT[dt][r]) * iv;
            }
        }
    }
    __syncthreads();                            // E3
    // coop convert + coalesced store: t -> q = t>>2, dg = t&3 (32 d values)
    {
        int q = t >> 2, dg = t & 3;
        size_t orow = ((size_t)(qbase + q) * 2 + ksh) * 128 + dg * 32;
        #pragma unroll
        for (int cc = 0; cc < 8; cc += 2) {
            int c0 = dg * 8 + cc;
            f32x4 u0 = *(const f32x4*)(obuf + q * 512 + (((c0 ^ (q & 31)) << 4)));
            f32x4 u1 = *(const f32x4*)(obuf + q * 512 + ((((c0 + 1) ^ (q & 31)) << 4)));
            bf16x8 ov;
            ov[0]=f2bf(u0[0]); ov[1]=f2bf(u0[1]); ov[2]=f2bf(u0[2]); ov[3]=f2bf(u0[3]);
            ov[4]=f2bf(u1[0]); ov[5]=f2bf(u1[1]); ov[6]=f2bf(u1[2]); ov[7]=f2bf(u1[3]);
            *(bf16x8*)(opart + orow + cc * 4) = ov;
        }
    }
}

// ---------------- out: combine k-halves, then gamma*(o@Wo + bo) + x ----------
__global__ __launch_bounds__(256) void out_kernel(
    const short* __restrict__ opart, const float* __restrict__ lspart,
    const short* __restrict__ WoT,
    const float* __restrict__ bo, const float* __restrict__ gamma,
    const float* __restrict__ x, float* __restrict__ out)
{
    int wid = threadIdx.x >> 6, lane = threadIdx.x & 63;
    int col16 = lane & 15, rq = lane >> 4;
    int rbase = blockIdx.x * 64 + wid * 16;
    int arow = rbase + col16;

    float l0 = lspart[(size_t)arow * 2];
    float l1 = lspart[(size_t)arow * 2 + 1];
    float iv = 1.f / (l0 + l1);
    float w0 = l0 * iv, w1 = l1 * iv;

    const short* oprow = opart + (size_t)arow * 256;
    bf16x8 afr[4];
    #pragma unroll
    for (int kk = 0; kk < 4; ++kk) {
        bf16x8 a0 = *(const bf16x8*)(oprow + kk * 32 + rq * 8);
        bf16x8 a1 = *(const bf16x8*)(oprow + 128 + kk * 32 + rq * 8);
        bf16x8 af;
        #pragma unroll
        for (int j = 0; j < 8; ++j)
            af[j] = f2bf(w0 * bf2f(a0[j]) + w1 * bf2f(a1[j]));
        afr[kk] = af;
    }

    f32x4 acc[16];
    #pragma unroll
    for (int i = 0; i < 16; ++i) acc[i] = (f32x4){0.f, 0.f, 0.f, 0.f};

    #pragma unroll
    for (int nf = 0; nf < 16; ++nf) {
        #pragma unroll
        for (int kk = 0; kk < 4; ++kk) {
            bf16x8 bfr = *(const bf16x8*)(WoT + (nf * 16 + col16) * DV + kk * 32 + rq * 8);
            acc[nf] = __builtin_amdgcn_mfma_f32_16x16x32_bf16(afr[kk], bfr, acc[nf], 0, 0, 0);
        }
    }

    float gm = gamma[0];
    #pragma unroll
    for (int nf = 0; nf < 16; ++nf) {
        int colg = nf * 16 + col16;
        float bov = bo[colg];
        #pragma unroll
        for (int r = 0; r < 4; ++r) {
            int rowg = rbase + rq * 4 + r;
            out[(size_t)rowg * CC + colg] = gm * (acc[nf][r] + bov) + x[(size_t)rowg * CC + colg];
        }
    }
}

extern "C" void kernel_launch(void* const* d_in, const int* in_sizes, int n_in,
                              void* d_out, int out_size, void* d_ws, size_t ws_size,
                              hipStream_t stream)
{
    const float* x     = (const float*)d_in[0];
    const float* Wf    = (const float*)d_in[1];
    const float* bf_   = (const float*)d_in[2];
    const float* Wg    = (const float*)d_in[3];
    const float* bg_   = (const float*)d_in[4];
    const float* Wh    = (const float*)d_in[5];
    const float* bh_   = (const float*)d_in[6];
    const float* Wo    = (const float*)d_in[7];
    const float* bo    = (const float*)d_in[8];
    const float* gamma = (const float*)d_in[9];

    char* ws = (char*)d_ws;
    short* fws   = (short*)(ws + OFF_F);
    short* gws   = (short*)(ws + OFF_G);
    short* vtile = (short*)(ws + OFF_VT);
    short* opart = (short*)(ws + OFF_OP);
    float* lsp   = (float*)(ws + OFF_LS);
    short* WqkvT = (short*)(ws + OFF_WQKVT);
    short* WoT   = (short*)(ws + OFF_WOT);
    float* out   = (float*)d_out;

    hipLaunchKernelGGL(prep_kernel, dim3(320), dim3(256), 0, stream, Wf, Wg, Wh, Wo, WqkvT, WoT);
    hipLaunchKernelGGL(proj_kernel, dim3(512), dim3(256), 0, stream,
                       x, bf_, bg_, bh_, WqkvT, fws, gws, vtile);
    hipLaunchKernelGGL(attn_kernel, dim3(1024), dim3(256), 0, stream, fws, gws, vtile, opart, lsp);
    hipLaunchKernelGGL(out_kernel, dim3(512), dim3(256), 0, stream, opart, lsp, WoT, bo, gamma, x, out);
}